// Round 1
// baseline (782.450 us; speedup 1.0000x reference)
//
#include <hip/hip_runtime.h>

#define N_ROUTES 512
#define N_TIMES  4096
#define N_MOVES  16384
#define N_NODES  2048
#define N_CDF    8192
#define ALPHA    0.15f
#define ROUTE_CAP 96   // Binomial(512,0.05): mean 25.6, std 4.9 -> 96 is >14 sigma
#define NODE_CAP  64   // Binomial(16384,1/2048): mean 8 -> 64 is absurdly safe

// ---------------- workspace layout (bytes) ----------------
// node_flow : float [N_NODES*N_TIMES]            off 0          size 33,554,432
// rcnt      : int   [N_MOVES]                    off 33,554,432 size 65,536
// rlist     : u16   [N_MOVES*ROUTE_CAP]          off 33,619,968 size 3,145,728
// ncnt      : int   [N_NODES]                    off 36,765,696 size 8,192
// nlist     : int   [N_NODES*NODE_CAP]           off 36,773,888 size 524,288
// total ~37.3 MB

__global__ __launch_bounds__(256) void relu_kernel(const float4* __restrict__ xr,
                                                   float4* __restrict__ xo, int n4) {
    int i = blockIdx.x * blockDim.x + threadIdx.x;
    if (i < n4) {
        float4 v = xr[i];
        v.x = fmaxf(v.x, 0.f); v.y = fmaxf(v.y, 0.f);
        v.z = fmaxf(v.z, 0.f); v.w = fmaxf(v.w, 0.f);
        xo[i] = v;
    }
}

// One thread per movement: scan its A row (512 floats, 0/1) and record route indices.
__global__ __launch_bounds__(256) void build_routes(const float4* __restrict__ A4,
                                                    int* __restrict__ rcnt,
                                                    unsigned short* __restrict__ rlist) {
    int m = blockIdx.x * blockDim.x + threadIdx.x;
    if (m >= N_MOVES) return;
    int cnt = 0;
    unsigned short* out = rlist + (size_t)m * ROUTE_CAP;
    const float4* row = A4 + (size_t)m * (N_ROUTES / 4);
    for (int i = 0; i < N_ROUTES / 4; ++i) {
        float4 v = row[i];
        int k = i * 4;
        if (v.x != 0.f && cnt < ROUTE_CAP) out[cnt++] = (unsigned short)(k);
        if (v.y != 0.f && cnt < ROUTE_CAP) out[cnt++] = (unsigned short)(k + 1);
        if (v.z != 0.f && cnt < ROUTE_CAP) out[cnt++] = (unsigned short)(k + 2);
        if (v.w != 0.f && cnt < ROUTE_CAP) out[cnt++] = (unsigned short)(k + 3);
    }
    rcnt[m] = cnt;
}

// Inverse index: node -> list of movements (order nondeterministic; only affects
// fp32 summation order of node_flow, well under threshold).
__global__ __launch_bounds__(256) void build_nodes(const int* __restrict__ mnode,
                                                   int* __restrict__ ncnt,
                                                   int* __restrict__ nlist) {
    int m = blockIdx.x * blockDim.x + threadIdx.x;
    if (m >= N_MOVES) return;
    int n = mnode[m];
    int slot = atomicAdd(&ncnt[n], 1);
    if (slot < NODE_CAP) nlist[(size_t)n * NODE_CAP + slot] = m;
}

// Fused: for each (node, 1024-col tile), compute every c_pred row of that node's
// movements (sparse sum over its routes) and accumulate node_flow in registers.
// No atomics, no c_pred re-read.
__global__ __launch_bounds__(256) void cpred_nodeflow(const float* __restrict__ x,
                                                      const int* __restrict__ ncnt,
                                                      const int* __restrict__ nlist,
                                                      const int* __restrict__ rcnt,
                                                      const unsigned short* __restrict__ rlist,
                                                      float* __restrict__ c_pred,
                                                      float* __restrict__ node_flow) {
    int n = blockIdx.x;
    int col = blockIdx.y * 1024 + threadIdx.x * 4;
    int cnt = ncnt[n];
    if (cnt > NODE_CAP) cnt = NODE_CAP;
    float4 nf = {0.f, 0.f, 0.f, 0.f};
    for (int j = 0; j < cnt; ++j) {
        int m = nlist[(size_t)n * NODE_CAP + j];           // wave-uniform
        int rc = rcnt[m];
        const unsigned short* rl = rlist + (size_t)m * ROUTE_CAP;
        float4 acc = {0.f, 0.f, 0.f, 0.f};
        for (int i = 0; i < rc; ++i) {
            int r = rl[i];                                  // wave-uniform (s_load)
            const float4 v = *(const float4*)(x + (size_t)r * N_TIMES + col);
            acc.x += v.x; acc.y += v.y; acc.z += v.z; acc.w += v.w;
        }
        *(float4*)(c_pred + (size_t)m * N_TIMES + col) = acc;
        nf.x += acc.x; nf.y += acc.y; nf.z += acc.z; nf.w += acc.w;
    }
    *(float4*)(node_flow + (size_t)n * N_TIMES + col) = nf;
}

// BPR epilogue: grid (col_tiles, c_chunks); each block sums 128 cdf rows for its
// 256 cols, then one atomicAdd per (block,col) into y (pre-zeroed).
__global__ __launch_bounds__(256) void bpr_kernel(const float* __restrict__ node_flow,
                                                  const float* __restrict__ t_free,
                                                  const float* __restrict__ cap,
                                                  const float* __restrict__ radio,
                                                  const int* __restrict__ cdf_node,
                                                  float* __restrict__ y) {
    int col = blockIdx.x * 256 + threadIdx.x;
    int c0 = blockIdx.y * 128;
    float acc = 0.f;
    for (int c = c0; c < c0 + 128; ++c) {
        int nd = cdf_node[c];                               // wave-uniform
        float tr = t_free[c] * radio[c];
        float invcap = 1.0f / cap[c];
        float flow = node_flow[(size_t)nd * N_TIMES + col]; // coalesced
        float ratio = fmaxf(flow * invcap, 1e-6f);
        float r2 = ratio * ratio;
        acc += tr + (ALPHA * tr) * (r2 * r2);
    }
    atomicAdd(&y[col], acc);
}

extern "C" void kernel_launch(void* const* d_in, const int* in_sizes, int n_in,
                              void* d_out, int out_size, void* d_ws, size_t ws_size,
                              hipStream_t stream) {
    const float* x_raw         = (const float*)d_in[0];
    const float* A             = (const float*)d_in[1];
    const float* t_free        = (const float*)d_in[2];
    const float* cap           = (const float*)d_in[3];
    const float* radio         = (const float*)d_in[4];
    const int*   movement_node = (const int*)d_in[5];
    const int*   cdf_node      = (const int*)d_in[6];

    float* out    = (float*)d_out;
    float* x_out  = out;                                           // 512*4096
    float* c_pred = out + (size_t)N_ROUTES * N_TIMES;              // 16384*4096
    float* y      = c_pred + (size_t)N_MOVES * N_TIMES;            // 4096

    char* ws = (char*)d_ws;
    float*          node_flow = (float*)(ws);
    int*            rcnt      = (int*)(ws + 33554432);
    unsigned short* rlist     = (unsigned short*)(ws + 33619968);
    int*            ncnt      = (int*)(ws + 36765696);
    int*            nlist     = (int*)(ws + 36773888);

    hipMemsetAsync(ncnt, 0, N_NODES * sizeof(int), stream);
    hipMemsetAsync(y, 0, N_TIMES * sizeof(float), stream);

    relu_kernel<<<dim3((N_ROUTES * N_TIMES / 4 + 255) / 256), dim3(256), 0, stream>>>(
        (const float4*)x_raw, (float4*)x_out, N_ROUTES * N_TIMES / 4);

    build_routes<<<dim3(N_MOVES / 256), dim3(256), 0, stream>>>(
        (const float4*)A, rcnt, rlist);

    build_nodes<<<dim3(N_MOVES / 256), dim3(256), 0, stream>>>(
        movement_node, ncnt, nlist);

    cpred_nodeflow<<<dim3(N_NODES, N_TIMES / 1024), dim3(256), 0, stream>>>(
        x_out, ncnt, nlist, rcnt, rlist, c_pred, node_flow);

    bpr_kernel<<<dim3(N_TIMES / 256, N_CDF / 128), dim3(256), 0, stream>>>(
        node_flow, t_free, cap, radio, cdf_node, y);
}

// Round 2
// 681.031 us; speedup vs baseline: 1.1489x; 1.1489x over previous
//
#include <hip/hip_runtime.h>

#define N_ROUTES 512
#define N_TIMES  4096
#define N_MOVES  16384
#define N_NODES  2048
#define N_CDF    8192
#define ALPHA    0.15f
#define ROUTE_CAP 96   // padded-to-4 route list per movement; realistic max ~50
#define NODE_CAP  32   // Binomial(16384,1/2048): mean 8 -> P(>32) ~ 5e-8 total
#define XSTRIDE  68    // 64 cols + 4 pad floats (keeps 16B align, spreads banks)

// ---------------- workspace layout (bytes) ----------------
// node_flow : float [2048*4096]        off 0           33,554,432
// rcnt      : int   [16384]            off 33,554,432      65,536
// rlist     : u16   [16384*96]         off 33,619,968   3,145,728
// ncnt      : int   [2048]             off 36,765,696       8,192
// nlist     : int   [2048*32]          off 36,773,888     262,144
// noff      : int   [2048]             off 37,036,032       8,192
// perm      : int   [16384]            off 37,044,224      65,536
// nid       : int   [16384]            off 37,109,760      65,536
// w         : float [2048]             off 37,175,296       8,192
// base      : float [1]                off 37,183,488         256
// total ~37.18 MB (<= round-1's 37.3 MB footprint)

__global__ __launch_bounds__(256) void relu_kernel(const float4* __restrict__ xr,
                                                   float4* __restrict__ xo, int n4) {
    int i = blockIdx.x * blockDim.x + threadIdx.x;
    if (i < n4) {
        float4 v = xr[i];
        v.x = fmaxf(v.x, 0.f); v.y = fmaxf(v.y, 0.f);
        v.z = fmaxf(v.z, 0.f); v.w = fmaxf(v.w, 0.f);
        xo[i] = v;
    }
}

// One WAVE per movement row: coalesced read of 512 floats, ballot-free prefix
// compaction of nonzero route indices. List padded to multiple of 4 with
// sentinel route 512 (a zeroed LDS row in the main kernel).
__global__ __launch_bounds__(256) void build_routes(const float* __restrict__ A,
                                                    int* __restrict__ rcnt,
                                                    unsigned short* __restrict__ rlist) {
    int m    = (blockIdx.x * 256 + threadIdx.x) >> 6;
    int lane = threadIdx.x & 63;
    const float* row = A + (size_t)m * N_ROUTES;
    float4 a = *(const float4*)(row + lane * 4);          // cols lane*4..+3
    float4 b = *(const float4*)(row + 256 + lane * 4);    // cols 256+lane*4..+3
    unsigned mask = 0;
    if (a.x != 0.f) mask |= 1u;  if (a.y != 0.f) mask |= 2u;
    if (a.z != 0.f) mask |= 4u;  if (a.w != 0.f) mask |= 8u;
    if (b.x != 0.f) mask |= 16u; if (b.y != 0.f) mask |= 32u;
    if (b.z != 0.f) mask |= 64u; if (b.w != 0.f) mask |= 128u;
    int c = __popc(mask);
    // inclusive wave scan of c
    int off = c;
    #pragma unroll
    for (int d = 1; d < 64; d <<= 1) {
        int t = __shfl_up(off, d);
        if (lane >= d) off += t;
    }
    int total = __shfl(off, 63);
    int k = off - c;                                      // exclusive prefix
    unsigned short* out = rlist + (size_t)m * ROUTE_CAP;
    int i0 = lane * 4, i1 = 256 + lane * 4;
    if (mask & 1u)   { if (k < ROUTE_CAP) out[k] = (unsigned short)(i0);     k++; }
    if (mask & 2u)   { if (k < ROUTE_CAP) out[k] = (unsigned short)(i0 + 1); k++; }
    if (mask & 4u)   { if (k < ROUTE_CAP) out[k] = (unsigned short)(i0 + 2); k++; }
    if (mask & 8u)   { if (k < ROUTE_CAP) out[k] = (unsigned short)(i0 + 3); k++; }
    if (mask & 16u)  { if (k < ROUTE_CAP) out[k] = (unsigned short)(i1);     k++; }
    if (mask & 32u)  { if (k < ROUTE_CAP) out[k] = (unsigned short)(i1 + 1); k++; }
    if (mask & 64u)  { if (k < ROUTE_CAP) out[k] = (unsigned short)(i1 + 2); k++; }
    if (mask & 128u) { if (k < ROUTE_CAP) out[k] = (unsigned short)(i1 + 3); k++; }
    int padded = (total + 3) & ~3;
    if (lane < padded - total) {
        int p = total + lane;
        if (p < ROUTE_CAP) out[p] = (unsigned short)512;  // sentinel -> zero row
    }
    if (lane == 0) rcnt[m] = min(padded, ROUTE_CAP);
}

__global__ __launch_bounds__(256) void build_nodes(const int* __restrict__ mnode,
                                                   int* __restrict__ ncnt,
                                                   int* __restrict__ nlist) {
    int m = blockIdx.x * blockDim.x + threadIdx.x;
    if (m >= N_MOVES) return;
    int n = mnode[m];
    int slot = atomicAdd(&ncnt[n], 1);
    if (slot < NODE_CAP) nlist[(size_t)n * NODE_CAP + slot] = m;
}

// exclusive prefix over 2048 clamped counts, one block
__global__ __launch_bounds__(256) void scan2048(const int* __restrict__ ncnt,
                                                int* __restrict__ noff) {
    __shared__ int ls[256];
    int t = threadIdx.x;
    int v[8]; int s = 0;
    #pragma unroll
    for (int i = 0; i < 8; ++i) { v[i] = min(ncnt[t * 8 + i], NODE_CAP); s += v[i]; }
    ls[t] = s;
    __syncthreads();
    for (int d = 1; d < 256; d <<= 1) {
        int add = (t >= d) ? ls[t - d] : 0;
        __syncthreads();
        ls[t] += add;
        __syncthreads();
    }
    int run = (t == 0) ? 0 : ls[t - 1];
    #pragma unroll
    for (int i = 0; i < 8; ++i) { noff[t * 8 + i] = run; run += v[i]; }
}

__global__ __launch_bounds__(64) void flatten(const int* __restrict__ ncnt,
                                              const int* __restrict__ noff,
                                              const int* __restrict__ nlist,
                                              int* __restrict__ perm,
                                              int* __restrict__ nid) {
    int n = blockIdx.x, s = threadIdx.x;
    int cnt = min(ncnt[n], NODE_CAP);
    if (s < cnt) {
        int j = noff[n] + s;
        perm[j] = nlist[(size_t)n * NODE_CAP + s];
        nid[j]  = n;
    }
}

// Main fused kernel: LDS-staged x col-tile (512 routes + zero sentinel row x 64
// cols), movements processed in node-sorted order; c_pred written directly,
// node_flow accumulated in registers and flushed via atomics on node change.
__global__ __launch_bounds__(512) void cpred_nodeflow_lds(
        const float* __restrict__ x,
        const int* __restrict__ perm, const int* __restrict__ nid,
        const int* __restrict__ rcnt, const unsigned short* __restrict__ rlist,
        float* __restrict__ c_pred, float* __restrict__ node_flow) {
    __shared__ float xt[513 * XSTRIDE];
    int tid = threadIdx.x;
    int colbase = blockIdx.x * 64;
    // stage x tile: 512 rows x 64 cols, padded stride
    #pragma unroll
    for (int it = 0; it < 16; ++it) {
        int e = it * 512 + tid;
        int r = e >> 4, c = (e & 15) * 4;
        *(float4*)(xt + r * XSTRIDE + c) =
            *(const float4*)(x + (size_t)r * N_TIMES + colbase + c);
    }
    if (tid < 16) *(float4*)(xt + 512 * XSTRIDE + tid * 4) = make_float4(0.f, 0.f, 0.f, 0.f);
    __syncthreads();

    int grp = tid >> 4;                 // 0..31: movement group
    int col4 = (tid & 15) * 4;          // 0..60: this thread's 4 cols
    int jbase = blockIdx.y * 512 + grp * 16;
    float4 nf = make_float4(0.f, 0.f, 0.f, 0.f);
    int cur = -1;
    for (int k = 0; k < 16; ++k) {
        int j = jbase + k;
        int m = perm[j];
        int n = nid[j];
        if (n != cur) {
            if (cur >= 0) {
                float* p = node_flow + (size_t)cur * N_TIMES + colbase + col4;
                atomicAdd(p, nf.x); atomicAdd(p + 1, nf.y);
                atomicAdd(p + 2, nf.z); atomicAdd(p + 3, nf.w);
            }
            cur = n;
            nf = make_float4(0.f, 0.f, 0.f, 0.f);
        }
        int rc = rcnt[m];
        const unsigned short* rl = rlist + (size_t)m * ROUTE_CAP;
        float4 a = make_float4(0.f, 0.f, 0.f, 0.f);
        for (int i = 0; i < rc; i += 4) {
            ushort4 rr = *(const ushort4*)(rl + i);       // 8B aligned
            const float4 v0 = *(const float4*)(xt + rr.x * XSTRIDE + col4);
            const float4 v1 = *(const float4*)(xt + rr.y * XSTRIDE + col4);
            const float4 v2 = *(const float4*)(xt + rr.z * XSTRIDE + col4);
            const float4 v3 = *(const float4*)(xt + rr.w * XSTRIDE + col4);
            a.x += (v0.x + v1.x) + (v2.x + v3.x);
            a.y += (v0.y + v1.y) + (v2.y + v3.y);
            a.z += (v0.z + v1.z) + (v2.z + v3.z);
            a.w += (v0.w + v1.w) + (v2.w + v3.w);
        }
        *(float4*)(c_pred + (size_t)m * N_TIMES + colbase + col4) = a;
        nf.x += a.x; nf.y += a.y; nf.z += a.z; nf.w += a.w;
    }
    if (cur >= 0) {
        float* p = node_flow + (size_t)cur * N_TIMES + colbase + col4;
        atomicAdd(p, nf.x); atomicAdd(p + 1, nf.y);
        atomicAdd(p + 2, nf.z); atomicAdd(p + 3, nf.w);
    }
}

// per-node BPR coefficients: w[n] = sum_c alpha*t_free*radio*cap^-4 ; base = sum_c t_free*radio
__global__ __launch_bounds__(256) void wsum_kernel(const float* __restrict__ t_free,
                                                   const float* __restrict__ cap,
                                                   const float* __restrict__ radio,
                                                   const int* __restrict__ cdf_node,
                                                   float* __restrict__ w,
                                                   float* __restrict__ basep) {
    int c = blockIdx.x * 256 + threadIdx.x;
    float tr = t_free[c] * radio[c];
    float ic = 1.0f / cap[c];
    float ic2 = ic * ic;
    atomicAdd(&w[cdf_node[c]], ALPHA * tr * ic2 * ic2);
    float b = tr;
    #pragma unroll
    for (int d = 32; d >= 1; d >>= 1) b += __shfl_down(b, d);
    if ((threadIdx.x & 63) == 0) atomicAdd(basep, b);
}

// y[t] = base + sum_n w[n] * node_flow[n,t]^4
__global__ __launch_bounds__(256) void y_kernel(const float* __restrict__ node_flow,
                                                const float* __restrict__ w,
                                                const float* __restrict__ basep,
                                                float* __restrict__ y) {
    int col = blockIdx.x * 256 + threadIdx.x;
    int n0 = blockIdx.y * 128;
    float acc = (blockIdx.y == 0) ? *basep : 0.f;
    for (int n = n0; n < n0 + 128; ++n) {
        float f = node_flow[(size_t)n * N_TIMES + col];
        float f2 = f * f;
        acc += w[n] * f2 * f2;
    }
    atomicAdd(&y[col], acc);
}

extern "C" void kernel_launch(void* const* d_in, const int* in_sizes, int n_in,
                              void* d_out, int out_size, void* d_ws, size_t ws_size,
                              hipStream_t stream) {
    const float* x_raw         = (const float*)d_in[0];
    const float* A             = (const float*)d_in[1];
    const float* t_free        = (const float*)d_in[2];
    const float* cap           = (const float*)d_in[3];
    const float* radio         = (const float*)d_in[4];
    const int*   movement_node = (const int*)d_in[5];
    const int*   cdf_node      = (const int*)d_in[6];

    float* out    = (float*)d_out;
    float* x_out  = out;                                  // 512*4096
    float* c_pred = out + (size_t)N_ROUTES * N_TIMES;     // 16384*4096
    float* y      = c_pred + (size_t)N_MOVES * N_TIMES;   // 4096

    char* ws = (char*)d_ws;
    float*          node_flow = (float*)(ws);
    int*            rcnt      = (int*)(ws + 33554432);
    unsigned short* rlist     = (unsigned short*)(ws + 33619968);
    int*            ncnt      = (int*)(ws + 36765696);
    int*            nlist     = (int*)(ws + 36773888);
    int*            noff      = (int*)(ws + 37036032);
    int*            perm      = (int*)(ws + 37044224);
    int*            nid       = (int*)(ws + 37109760);
    float*          w         = (float*)(ws + 37175296);
    float*          basep     = (float*)(ws + 37183488);

    hipMemsetAsync(ncnt, 0, N_NODES * sizeof(int), stream);
    hipMemsetAsync(node_flow, 0, (size_t)N_NODES * N_TIMES * sizeof(float), stream);
    hipMemsetAsync(w, 0, N_NODES * sizeof(float), stream);
    hipMemsetAsync(basep, 0, sizeof(float), stream);
    hipMemsetAsync(y, 0, N_TIMES * sizeof(float), stream);

    relu_kernel<<<dim3((N_ROUTES * N_TIMES / 4 + 255) / 256), dim3(256), 0, stream>>>(
        (const float4*)x_raw, (float4*)x_out, N_ROUTES * N_TIMES / 4);

    build_routes<<<dim3(N_MOVES / 4), dim3(256), 0, stream>>>(A, rcnt, rlist);

    build_nodes<<<dim3(N_MOVES / 256), dim3(256), 0, stream>>>(movement_node, ncnt, nlist);

    scan2048<<<dim3(1), dim3(256), 0, stream>>>(ncnt, noff);

    flatten<<<dim3(N_NODES), dim3(64), 0, stream>>>(ncnt, noff, nlist, perm, nid);

    cpred_nodeflow_lds<<<dim3(N_TIMES / 64, N_MOVES / 512), dim3(512), 0, stream>>>(
        x_out, perm, nid, rcnt, rlist, c_pred, node_flow);

    wsum_kernel<<<dim3(N_CDF / 256), dim3(256), 0, stream>>>(
        t_free, cap, radio, cdf_node, w, basep);

    y_kernel<<<dim3(N_TIMES / 256, N_NODES / 128), dim3(256), 0, stream>>>(
        node_flow, w, basep, y);
}

// Round 3
// 406.305 us; speedup vs baseline: 1.9258x; 1.6762x over previous
//
#include <hip/hip_runtime.h>

#define N_ROUTES 512
#define N_TIMES  4096
#define N_MOVES  16384
#define N_NODES  2048
#define N_CDF    8192
#define ALPHA    0.15f
#define NODE_CAP 32    // Binomial(16384,1/2048): mean 8 -> P(>32) negligible

typedef unsigned short ushort_t;
typedef __attribute__((ext_vector_type(8))) short short8;
typedef __attribute__((ext_vector_type(4))) float floatx4;

// ---------------- workspace layout (bytes) ----------------
// Abig  : bf16 [18432*512]   off 0           18,874,368   (rows 0..16383 = A, 16384..18431 = SA)
// xTbf  : bf16 [4096*512]    off 18,874,368   4,194,304
// ncnt  : int  [2048]        off 23,068,672       8,192
// nlist : int  [2048*32]     off 23,076,864     262,144
// w     : f32  [2048]        off 23,339,008       8,192
// basep : f32  [1]           off 23,347,200         256
// total ~23.4 MB (round-1 proved ws >= 37 MB)

__device__ inline ushort_t f2bf(float f) {
    union { float f; unsigned u; } v; v.f = f;
    unsigned r = (v.u + 0x7FFFu + ((v.u >> 16) & 1u)) >> 16;
    return (ushort_t)r;
}

// output 0: x = relu(x_raw), fp32 exact
__global__ __launch_bounds__(256) void relu_kernel(const float4* __restrict__ xr,
                                                   float4* __restrict__ xo, int n4) {
    int i = blockIdx.x * blockDim.x + threadIdx.x;
    if (i < n4) {
        float4 v = xr[i];
        v.x = fmaxf(v.x, 0.f); v.y = fmaxf(v.y, 0.f);
        v.z = fmaxf(v.z, 0.f); v.w = fmaxf(v.w, 0.f);
        xo[i] = v;
    }
}

// xT[t][k] = bf16(relu(x_raw[k][t])) — LDS tile transpose, both sides coalesced
__global__ __launch_bounds__(256) void transpose_bf(const float* __restrict__ xr,
                                                    ushort_t* __restrict__ xT) {
    __shared__ float ld[64][65];
    int t0 = blockIdx.x * 64;
    int k0 = blockIdx.y * 64;
    int tid = threadIdx.x;
    int col = tid & 63;
    #pragma unroll
    for (int i = 0; i < 16; ++i) {
        int row = i * 4 + (tid >> 6);
        ld[row][col] = fmaxf(xr[(size_t)(k0 + row) * N_TIMES + t0 + col], 0.f);
    }
    __syncthreads();
    int trow = tid >> 2;
    int kgrp = (tid & 3) * 16;
    ushort_t __align__(16) tmp[16];
    #pragma unroll
    for (int j = 0; j < 16; ++j) tmp[j] = f2bf(ld[kgrp + j][trow]);
    ushort_t* dst = xT + (size_t)(t0 + trow) * 512 + k0 + kgrp;
    *(uint4*)dst       = ((uint4*)tmp)[0];
    *(uint4*)(dst + 8) = ((uint4*)tmp)[1];
}

// A fp32 -> bf16 (0/1 values: exact)
__global__ __launch_bounds__(256) void convA(const float* __restrict__ A,
                                             ushort_t* __restrict__ Ab) {
    size_t i = (size_t)(blockIdx.x * 256 + threadIdx.x) * 8;
    const float4* s = (const float4*)(A + i);
    float4 a = s[0], b = s[1];
    ushort_t __align__(16) t[8] = {f2bf(a.x), f2bf(a.y), f2bf(a.z), f2bf(a.w),
                                   f2bf(b.x), f2bf(b.y), f2bf(b.z), f2bf(b.w)};
    *(uint4*)(Ab + i) = *(uint4*)t;
}

__global__ __launch_bounds__(256) void build_nodes(const int* __restrict__ mnode,
                                                   int* __restrict__ ncnt,
                                                   int* __restrict__ nlist) {
    int m = blockIdx.x * blockDim.x + threadIdx.x;
    if (m >= N_MOVES) return;
    int n = mnode[m];
    int slot = atomicAdd(&ncnt[n], 1);
    if (slot < NODE_CAP) nlist[(size_t)n * NODE_CAP + slot] = m;
}

// SA[n][k] = sum over movements of node n of A[m][k] (small ints, exact in bf16)
__global__ __launch_bounds__(128) void sa_kernel(const float* __restrict__ A,
                                                 const int* __restrict__ ncnt,
                                                 const int* __restrict__ nlist,
                                                 ushort_t* __restrict__ SAb) {
    int n = blockIdx.x, tid = threadIdx.x;
    int cnt = min(ncnt[n], NODE_CAP);
    float acc0 = 0.f, acc1 = 0.f, acc2 = 0.f, acc3 = 0.f;
    for (int j = 0; j < cnt; ++j) {
        int m = nlist[(size_t)n * NODE_CAP + j];
        float4 v = *(const float4*)(A + (size_t)m * 512 + tid * 4);
        acc0 += v.x; acc1 += v.y; acc2 += v.z; acc3 += v.w;
    }
    ushort_t __align__(8) t[4] = {f2bf(acc0), f2bf(acc1), f2bf(acc2), f2bf(acc3)};
    *(uint2*)(SAb + (size_t)n * 512 + tid * 4) = *(uint2*)t;
}

// w[n] = sum_c alpha*t_free*radio/cap^4 ; base = sum_c t_free*radio
__global__ __launch_bounds__(256) void wsum_kernel(const float* __restrict__ t_free,
                                                   const float* __restrict__ cap,
                                                   const float* __restrict__ radio,
                                                   const int* __restrict__ cdf_node,
                                                   float* __restrict__ w,
                                                   float* __restrict__ basep) {
    int c = blockIdx.x * 256 + threadIdx.x;
    float tr = t_free[c] * radio[c];
    float ic = 1.0f / cap[c];
    float ic2 = ic * ic;
    atomicAdd(&w[cdf_node[c]], ALPHA * tr * ic2 * ic2);
    float b = tr;
    #pragma unroll
    for (int d = 32; d >= 1; d >>= 1) b += __shfl_down(b, d);
    if ((threadIdx.x & 63) == 0) atomicAdd(basep, b);
}

__global__ __launch_bounds__(256) void y_init(const float* __restrict__ basep,
                                              float* __restrict__ y) {
    y[blockIdx.x * 256 + threadIdx.x] = *basep;
}

#define GLOAD_LDS16(g, l) __builtin_amdgcn_global_load_lds( \
    (const __attribute__((address_space(1))) void*)(g),     \
    (__attribute__((address_space(3))) void*)(l), 16, 0, 0)

// Fused GEMM: C[18432 x 4096] = Abig @ xT^T, bf16 MFMA 16x16x32.
// Rows < 16384 -> c_pred (written).  Rows >= 16384 are nodes -> y += w[n]*f^4
// reduced in-register, never materialized.
// Tile 128x128, BK=64, 256 thr (4 waves, 64x64 quadrant each).
// LDS XOR-swizzle: 16B chunk c stored at c ^ (row&7) — conflict-free b128 reads,
// and staging stays lane-linear for global_load_lds.
__global__ __launch_bounds__(256) void gemm_fused(const ushort_t* __restrict__ Abig,
                                                  const ushort_t* __restrict__ Bbf,
                                                  float* __restrict__ c_pred,
                                                  const float* __restrict__ w,
                                                  float* __restrict__ y) {
    __shared__ __align__(16) ushort_t Atile[128 * 64];
    __shared__ __align__(16) ushort_t Btile[128 * 64];

    const int tid  = threadIdx.x;
    const int wv   = tid >> 6;
    const int lane = tid & 63;
    const int quad = lane >> 4;
    const int l16  = lane & 15;
    const int bn   = blockIdx.x;   // col tile (fast-varying: A tile reuse in L2)
    const int bm   = blockIdx.y;   // row tile

    const int mi = (wv & 1) * 64;
    const int ni = (wv >> 1) * 64;

    floatx4 acc[4][4] = {};

    const int srow  = lane >> 3;       // 0..7 within 8-row staging chunk
    const int schk  = lane & 7;        // physical 16B chunk within row

    for (int kt = 0; kt < 8; ++kt) {
        if (kt) __syncthreads();       // previous iter's reads done
        #pragma unroll
        for (int c = 0; c < 4; ++c) {
            int rowbase = wv * 32 + c * 8;
            int row = rowbase + srow;
            int cl  = schk ^ (row & 7);
            const ushort_t* ga = Abig + (size_t)(bm * 128 + row) * 512 + kt * 64 + cl * 8;
            GLOAD_LDS16(ga, Atile + rowbase * 64);
            const ushort_t* gb = Bbf + (size_t)(bn * 128 + row) * 512 + kt * 64 + cl * 8;
            GLOAD_LDS16(gb, Btile + rowbase * 64);
        }
        __syncthreads();               // staging visible (vmcnt drained at barrier)

        #pragma unroll
        for (int kk = 0; kk < 2; ++kk) {
            short8 af[4], bf[4];
            #pragma unroll
            for (int fi = 0; fi < 4; ++fi) {
                int row = mi + fi * 16 + l16;
                int cp  = (kk * 4 + quad) ^ (row & 7);
                af[fi] = *(const short8*)(Atile + row * 64 + cp * 8);
            }
            #pragma unroll
            for (int fj = 0; fj < 4; ++fj) {
                int row = ni + fj * 16 + l16;
                int cp  = (kk * 4 + quad) ^ (row & 7);
                bf[fj] = *(const short8*)(Btile + row * 64 + cp * 8);
            }
            #pragma unroll
            for (int fi = 0; fi < 4; ++fi)
                #pragma unroll
                for (int fj = 0; fj < 4; ++fj)
                    acc[fi][fj] = __builtin_amdgcn_mfma_f32_16x16x32_bf16(
                        af[fi], bf[fj], acc[fi][fj], 0, 0, 0);
        }
    }

    if (bm < 128) {
        // movement rows: write c_pred
        #pragma unroll
        for (int fi = 0; fi < 4; ++fi) {
            #pragma unroll
            for (int reg = 0; reg < 4; ++reg) {
                size_t row = (size_t)bm * 128 + mi + fi * 16 + quad * 4 + reg;
                float* cp = c_pred + row * N_TIMES + bn * 128 + ni + l16;
                #pragma unroll
                for (int fj = 0; fj < 4; ++fj)
                    cp[fj * 16] = acc[fi][fj][reg];
            }
        }
    } else {
        // node rows: y[col] += sum_rows w[n] * f^4   (node id == row index)
        int nb = (bm - 128) * 128;
        float psum[4] = {0.f, 0.f, 0.f, 0.f};
        #pragma unroll
        for (int fj = 0; fj < 4; ++fj)
            #pragma unroll
            for (int fi = 0; fi < 4; ++fi)
                #pragma unroll
                for (int reg = 0; reg < 4; ++reg) {
                    int n = nb + mi + fi * 16 + quad * 4 + reg;
                    float f = acc[fi][fj][reg];
                    float f2 = f * f;
                    psum[fj] += w[n] * f2 * f2;
                }
        #pragma unroll
        for (int fj = 0; fj < 4; ++fj) {
            float v = psum[fj];
            v += __shfl_xor(v, 16);
            v += __shfl_xor(v, 32);
            if (quad == 0)
                atomicAdd(&y[bn * 128 + ni + fj * 16 + l16], v);
        }
    }
}

extern "C" void kernel_launch(void* const* d_in, const int* in_sizes, int n_in,
                              void* d_out, int out_size, void* d_ws, size_t ws_size,
                              hipStream_t stream) {
    const float* x_raw         = (const float*)d_in[0];
    const float* A             = (const float*)d_in[1];
    const float* t_free        = (const float*)d_in[2];
    const float* cap           = (const float*)d_in[3];
    const float* radio         = (const float*)d_in[4];
    const int*   movement_node = (const int*)d_in[5];
    const int*   cdf_node      = (const int*)d_in[6];

    float* out    = (float*)d_out;
    float* x_out  = out;                                  // 512*4096
    float* c_pred = out + (size_t)N_ROUTES * N_TIMES;     // 16384*4096
    float* y      = c_pred + (size_t)N_MOVES * N_TIMES;   // 4096

    char* ws = (char*)d_ws;
    ushort_t* Abig  = (ushort_t*)(ws);                    // 18432*512 bf16
    ushort_t* SAb   = Abig + (size_t)N_MOVES * 512;       // rows 16384..18431
    ushort_t* xTbf  = (ushort_t*)(ws + 18874368);         // 4096*512 bf16
    int*      ncnt  = (int*)(ws + 23068672);
    int*      nlist = (int*)(ws + 23076864);
    float*    w     = (float*)(ws + 23339008);
    float*    basep = (float*)(ws + 23347200);

    hipMemsetAsync(ncnt, 0, N_NODES * sizeof(int), stream);
    hipMemsetAsync(w, 0, N_NODES * sizeof(float), stream);
    hipMemsetAsync(basep, 0, sizeof(float), stream);

    relu_kernel<<<dim3((N_ROUTES * N_TIMES / 4 + 255) / 256), dim3(256), 0, stream>>>(
        (const float4*)x_raw, (float4*)x_out, N_ROUTES * N_TIMES / 4);

    transpose_bf<<<dim3(N_TIMES / 64, N_ROUTES / 64), dim3(256), 0, stream>>>(x_raw, xTbf);

    convA<<<dim3((int)((size_t)N_MOVES * 512 / 8 / 256)), dim3(256), 0, stream>>>(A, Abig);

    build_nodes<<<dim3(N_MOVES / 256), dim3(256), 0, stream>>>(movement_node, ncnt, nlist);

    sa_kernel<<<dim3(N_NODES), dim3(128), 0, stream>>>(A, ncnt, nlist, SAb);

    wsum_kernel<<<dim3(N_CDF / 256), dim3(256), 0, stream>>>(
        t_free, cap, radio, cdf_node, w, basep);

    y_init<<<dim3(N_TIMES / 256), dim3(256), 0, stream>>>(basep, y);

    gemm_fused<<<dim3(N_TIMES / 128, (N_MOVES + N_NODES) / 128), dim3(256), 0, stream>>>(
        Abig, xTbf, c_pred, w, y);
}